// Round 7
// baseline (307.816 us; speedup 1.0000x reference)
//
#include <hip/hip_runtime.h>

// Modulated deformable conv 3x3, in_ch=out_ch=1, stride=1, pad=1, dil=1.
// B=8, H=W=512. d_in order: depth, mask(weight), offset, w, b.
//
// R13: full-width strips -- fix the DRAM access shape.
//  - R12 post-mortem: async DMA gave guaranteed 27-deep MLP; time UNCHANGED
//    (~95us). R6/R11/R12 (MLP 2..27, occ 33-53%) all pinned at
//    unique_bytes/2.5TB/s. The invariant across rounds is the DRAM pattern:
//    payload read as 27 planes x 8 chunks of 128-256B strided 2KB (tile
//    width 32/64 < W). Sub-256B fragments hashed across 2048 blocks ->
//    row-buffer thrash -> ~2.5 TB/s effective + inflated latency (why MLP
//    and occupancy moves did nothing).
//  - Fix: block = 2 FULL rows (512 thr x 2 px). Payload per plane per block
//    = 4KB contiguous; 27 clean streams. Depth = 18-row full-width strip in
//    LDS (37.4KB, x=-1/512 zero pad columns keep edge samples exact);
//    4 blocks/CU -> 32 waves/CU (100% occupancy) as secondary lever.
//  - Consume = R6's proven f2 shape. Depth overfetch 9x accepted (3.5% of
//    traffic, L3-hot).

#define KK 9
#define PAD 1
#define H 512
#define W 512
#define HW (H * W)

#define STRIDE 520                       // tile row stride (floats), 16B-aligned
#define LROWS 18                         // 2 out rows + 2*8 halo
#define SAFE 8835u                       // 16*520 + 4 + 511: max legit base idx
                                         // (su+521 = 9356 <= 9359)

typedef float f2 __attribute__((ext_vector_type(2)));
typedef float f4 __attribute__((ext_vector_type(4)));

__device__ __forceinline__ float bilin_global(const float* __restrict__ img,
                                              float y, float x) {
    float y0f = floorf(y);
    float x0f = floorf(x);
    int y0 = (int)y0f;
    int x0 = (int)x0f;
    float wy = y - y0f;
    float wx = x - x0f;
    int y1 = y0 + 1;
    int x1 = x0 + 1;

    bool y0i = (y0 >= 0) & (y0 < H);
    bool y1i = (y1 >= 0) & (y1 < H);
    bool x0i = (x0 >= 0) & (x0 < W);
    bool x1i = (x1 >= 0) & (x1 < W);

    int y0c = min(max(y0, 0), H - 1);
    int y1c = min(max(y1, 0), H - 1);
    int x0c = min(max(x0, 0), W - 1);
    int x1c = min(max(x1, 0), W - 1);

    float v00 = (y0i & x0i) ? img[y0c * W + x0c] : 0.0f;
    float v01 = (y0i & x1i) ? img[y0c * W + x1c] : 0.0f;
    float v10 = (y1i & x0i) ? img[y1c * W + x0c] : 0.0f;
    float v11 = (y1i & x1i) ? img[y1c * W + x1c] : 0.0f;

    float omwy = 1.0f - wy;
    float omwx = 1.0f - wx;
    return fmaf(v00 * omwy, omwx,
           fmaf(v01 * omwy, wx,
           fmaf(v10 * wy,   omwx, v11 * wy * wx)));
}

// Branchless strip sample. syr: TILE-RELATIVE row; sxa: ABSOLUTE x.
// Tile col mapping: x -> 4 + x (x=-1 and x=512 are zero pad columns).
// Out-of-strip lanes read a clamped safe address and set oob; fixup recomputes.
__device__ __forceinline__ float sample_fw(const float* S, float syr, float sxa,
                                           int& oob) {
    const float y0f = floorf(syr);
    const float x0f = floorf(sxa);
    const float wy = syr - y0f;
    const float wx = sxa - x0f;
    const int ly = (int)y0f;
    const int x0 = (int)x0f;
    oob |= (int)(((unsigned)ly >= (unsigned)(LROWS - 1)) |
                 ((unsigned)(x0 + 1) >= 513u));
    unsigned su = (unsigned)(ly * STRIDE + 4 + x0);
    su = su < SAFE ? su : SAFE;          // v_min_u32: always-safe read
    const float v00 = S[su];
    const float v01 = S[su + 1];
    const float v10 = S[su + STRIDE];
    const float v11 = S[su + STRIDE + 1];
    const float omwy = 1.0f - wy;
    const float omwx = 1.0f - wx;
    return fmaf(v00 * omwy, omwx,
           fmaf(v01 * omwy, wx,
           fmaf(v10 * wy,   omwx, v11 * wy * wx)));
}

__global__ __launch_bounds__(512, 8) void dcn_kernel(
    const float* __restrict__ depth,
    const float* __restrict__ mask,
    const float* __restrict__ offset,
    const float* __restrict__ w9,
    const float* __restrict__ bias,
    float* __restrict__ out) {
    __shared__ float S[LROWS * STRIDE];  // 9360 floats = 37,440 B

    const int b  = blockIdx.z;
    const int by = blockIdx.y;           // strip index: rows [2by, 2by+1]
    const int tY0 = 2 * by - 8;          // strip row 0 in image coords

    const float* __restrict__ img = depth + (long)b * HW;
    const int tid = (int)threadIdx.x;

    // --- stage 18 full-width depth rows (+ zero pads at x=-1, x=512).
    // Interior: 18 rows x 128 aligned f4 chunks = 2304 chunks, 4.5 rounds. ---
    #pragma unroll
    for (int j = 0; j < 5; ++j) {
        const int c = tid + j * 512;
        if (c < LROWS * 128) {
            const int ly = c >> 7;                  // 0..17
            const int cx = (c & 127) << 2;          // 0,4,..,508
            const int gy = tY0 + ly;
            const int ok = (int)((unsigned)gy < (unsigned)H);
            const f4 v = *(const f4*)(img + (ok ? (gy * W + cx) : 0));
            f4 z;
            z.x = ok ? v.x : 0.0f;
            z.y = ok ? v.y : 0.0f;
            z.z = ok ? v.z : 0.0f;
            z.w = ok ? v.w : 0.0f;
            *(f4*)(S + ly * STRIDE + 4 + cx) = z;
        }
    }
    if (tid < 2 * LROWS) {
        const int r = tid >> 1;
        S[r * STRIDE + ((tid & 1) ? 516 : 3)] = 0.0f;
    }

    // 2 consecutive px/thread on rows 2by / 2by+1
    const int xp = tid & 255;            // x-pair 0..255
    const int yr = tid >> 8;             // 0..1
    const int tx = 2 * xp;
    const int ty = 2 * by + yr;
    const int pix = ty * W + tx;

    const float* __restrict__ mskp = mask   + ((long)b * KK)     * HW + pix;
    const float* __restrict__ offp = offset + ((long)b * 2 * KK) * HW + pix;

    // payload: 27 dwordx2 loads (compiler-owned). Per plane per block the
    // block's footprint is 4KB CONTIGUOUS -> clean DRAM streams.
    f2 dy0, dy1, dy2, dy3, dy4, dy5, dy6, dy7, dy8;
    f2 dx0, dx1, dx2, dx3, dx4, dx5, dx6, dx7, dx8;
    f2 m0, m1, m2, m3, m4, m5, m6, m7, m8;
#define LDT(k)                                               \
    dy##k = *(const f2*)(offp + (2 * k) * HW);               \
    dx##k = *(const f2*)(offp + (2 * k + 1) * HW);           \
    m##k  = *(const f2*)(mskp + k * HW);
    LDT(0) LDT(1) LDT(2) LDT(3) LDT(4) LDT(5) LDT(6) LDT(7) LDT(8)
#undef LDT

    // uniform taps
    const float wk0 = w9[0], wk1 = w9[1], wk2 = w9[2];
    const float wk3 = w9[3], wk4 = w9[4], wk5 = w9[5];
    const float wk6 = w9[6], wk7 = w9[7], wk8 = w9[8];
    const float bs = bias[0];

    __syncthreads();

    float a0 = bs, a1 = bs;
    int oob = 0;
    // tile-relative base row: ty - PAD - tY0 = yr + 7; absolute base x: tx - 1
    const float sybr = (float)(yr + 7);
    const float sxbr = (float)(tx - 1);

    // --- consume: branchless, fully unrolled, pure VALU+LDS ---
#define CTAP(k, KYC, KXC, WK)                                                 \
    {                                                                         \
        const float syk = sybr + (float)(KYC);                                \
        const float sxk = sxbr + (float)(KXC);                                \
        a0 = fmaf(sample_fw(S, syk + dy##k.x, sxk + 0.0f + dx##k.x, oob),     \
                  m##k.x * (WK), a0);                                         \
        a1 = fmaf(sample_fw(S, syk + dy##k.y, sxk + 1.0f + dx##k.y, oob),     \
                  m##k.y * (WK), a1);                                         \
    }
    CTAP(0, 0, 0, wk0) CTAP(1, 0, 1, wk1) CTAP(2, 0, 2, wk2)
    CTAP(3, 1, 0, wk3) CTAP(4, 1, 1, wk4) CTAP(5, 1, 2, wk5)
    CTAP(6, 2, 0, wk6) CTAP(7, 2, 1, wk7) CTAP(8, 2, 2, wk8)
#undef CTAP

    // --- rare fixup: |dy| >= ~7 only (x edges are exact via pad columns).
    // Recompute whole pixel pair via the global path; wave-uniform skip. ---
    if (__builtin_expect(__any(oob), 0)) {
        if (oob) {
            a0 = bs;
            a1 = bs;
#pragma unroll 1
            for (int k = 0; k < KK; ++k) {
                const int ky = k / 3;
                const int kx = k - 3 * ky;
                const float wk = w9[k];
                const float fdy0 = offp[(2 * k) * HW];
                const float fdy1 = offp[(2 * k) * HW + 1];
                const float fdx0 = offp[(2 * k + 1) * HW];
                const float fdx1 = offp[(2 * k + 1) * HW + 1];
                const float fm0 = mskp[k * HW];
                const float fm1 = mskp[k * HW + 1];
                const float syA = (float)(ty - PAD + ky) + fdy0;
                const float sxA = (float)(tx - PAD + kx) + fdx0;
                a0 = fmaf(bilin_global(img, syA, sxA), fm0 * wk, a0);
                const float syB = (float)(ty - PAD + ky) + fdy1;
                const float sxB = (float)(tx - PAD + kx + 1) + fdx1;
                a1 = fmaf(bilin_global(img, syB, sxB), fm1 * wk, a1);
            }
        }
    }

    f2 r;
    r.x = a0;
    r.y = a1;
    *(f2*)(out + (long)b * HW + pix) = r;
}

extern "C" void kernel_launch(void* const* d_in, const int* in_sizes, int n_in,
                              void* d_out, int out_size, void* d_ws, size_t ws_size,
                              hipStream_t stream) {
    const float* depth  = (const float*)d_in[0];
    const float* mask   = (const float*)d_in[1];   // reference's "weight" arg = modulation mask
    const float* offset = (const float*)d_in[2];
    const float* w9     = (const float*)d_in[3];
    const float* bias   = (const float*)d_in[4];
    float* out = (float*)d_out;

    const int B = in_sizes[0] / HW;   // = 8

    dim3 block(512);
    dim3 grid(1, H / 2, B);           // (1, 256, 8)
    dcn_kernel<<<grid, block, 0, stream>>>(depth, mask, offset, w9, bias, out);
}